// Round 3
// baseline (435.969 us; speedup 1.0000x reference)
//
#include <hip/hip_runtime.h>

// N=100000, E=6400000. Buckets of 128 nodes -> NB=782.
// TILE=12500 -> T=512 tiles exactly: 2 blocks/CU uniformly (62KB LDS), no imbalance round.
constexpr int TILE  = 12500;  // edges per tile (divisible by 4)
constexpr int TPBP  = 1024;   // threads for k_part
constexpr int TPB   = 512;    // threads for k_l1f / k_l2
constexpr int NPB   = 128;    // nodes per bucket
constexpr int NBMAX = 1024;   // LDS sizing bound for NB
constexpr int MAXBE = 9216;   // max edges per bucket (mean 8192, +11 sigma; multiple of 32)
constexpr int EPT   = MAXBE / TPB;  // 18 edges per thread in k_l1f

__device__ __forceinline__ int sw(int j)  { return j ^ (((j >> 7) & 7) << 2); }  // word swizzle
__device__ __forceinline__ int sw4(int j) { return j ^ ((j >> 5) & 7); }         // int4 swizzle

// ---- fused hist + rank(regs) + reserve + LDS-sort + 16-lane flush + global deg atomics ----
__global__ __launch_bounds__(TPBP, 8) void k_part(const int* __restrict__ src,
                                                  const int* __restrict__ dst,
                                                  int E, int NB,
                                                  int* __restrict__ cursor,
                                                  unsigned int* __restrict__ spack,
                                                  int* __restrict__ degn) {
    __shared__ int h[NBMAX];
    __shared__ int lofs[NBMAX];
    __shared__ int startb[NBMAX];
    __shared__ unsigned int sorted[TILE];  // 50 KB

    int tid = threadIdx.x;
    int t = blockIdx.x;
    for (int j = tid; j < NBMAX; j += TPBP) h[j] = 0;
    __syncthreads();

    const int4* dv = reinterpret_cast<const int4*>(dst);
    const int4* sv = reinterpret_cast<const int4*>(src);
    int ebeg = t * TILE;
    int base4 = ebeg >> 2;
    int eend = ebeg + TILE; if (eend > E) eend = E;
    int n4t = (eend - ebeg + 3) >> 2;  // int4 slots in this tile (3125 for full tile)

    unsigned short rr[16];  // per-edge rank within (tile,bucket)

    // pass A: LDS histogram (rank in regs) + global per-node degree atomics (fire-and-forget)
#pragma unroll
    for (int k = 0; k < (TILE / 4 + TPBP - 1) / TPBP; ++k) {  // 4 iters
        int idx = k * TPBP + tid;
        if (idx < n4t) {
            int i4 = base4 + idx;
            int e = i4 * 4;
            if (e + 4 <= E) {
                int4 d = dv[i4];
                rr[k * 4 + 0] = (unsigned short)atomicAdd(&h[d.x >> 7], 1);
                rr[k * 4 + 1] = (unsigned short)atomicAdd(&h[d.y >> 7], 1);
                rr[k * 4 + 2] = (unsigned short)atomicAdd(&h[d.z >> 7], 1);
                rr[k * 4 + 3] = (unsigned short)atomicAdd(&h[d.w >> 7], 1);
                atomicAdd(&degn[d.x], 1);
                atomicAdd(&degn[d.y], 1);
                atomicAdd(&degn[d.z], 1);
                atomicAdd(&degn[d.w], 1);
            } else {
#pragma unroll
                for (int j = 0; j < 4; ++j) {
                    int e2 = e + j;
                    if (e2 < E) {
                        int d = dst[e2];
                        rr[k * 4 + j] = (unsigned short)atomicAdd(&h[d >> 7], 1);
                        atomicAdd(&degn[d], 1);
                    }
                }
            }
        }
    }
    __syncthreads();

    // reserve global space per bucket
    for (int b = tid; b < NB; b += TPBP)
        startb[b] = atomicAdd(&cursor[b], h[b]);

    // tile-local exclusive scan of h -> lofs (wave 0)
    if (tid < 64) {
        int run = 0;
        for (int c = 0; c < NBMAX; c += 64) {
            int b = c + tid;
            int v = (b < NB) ? h[b] : 0;
            int inc = v;
#pragma unroll
            for (int d = 1; d < 64; d <<= 1) {
                int o = __shfl_up(inc, d);
                if (tid >= d) inc += o;
            }
            if (b < NB) lofs[b] = run + inc - v;
            run += __shfl(inc, 63);
        }
    }
    __syncthreads();

    // pass B: re-read src/dst (L2-warm), scatter packed edges into LDS-sorted tile
#pragma unroll
    for (int k = 0; k < (TILE / 4 + TPBP - 1) / TPBP; ++k) {
        int idx = k * TPBP + tid;
        if (idx < n4t) {
            int i4 = base4 + idx;
            int e = i4 * 4;
            if (e + 4 <= E) {
                int4 d = dv[i4];
                int4 s = sv[i4];
                sorted[lofs[d.x >> 7] + (int)rr[k * 4 + 0]] = ((unsigned)s.x << 7) | (unsigned)(d.x & 127);
                sorted[lofs[d.y >> 7] + (int)rr[k * 4 + 1]] = ((unsigned)s.y << 7) | (unsigned)(d.y & 127);
                sorted[lofs[d.z >> 7] + (int)rr[k * 4 + 2]] = ((unsigned)s.z << 7) | (unsigned)(d.z & 127);
                sorted[lofs[d.w >> 7] + (int)rr[k * 4 + 3]] = ((unsigned)s.w << 7) | (unsigned)(d.w & 127);
            } else {
#pragma unroll
                for (int j = 0; j < 4; ++j) {
                    int e2 = e + j;
                    if (e2 < E) {
                        int d = dst[e2];
                        int s = src[e2];
                        sorted[lofs[d >> 7] + (int)rr[k * 4 + j]] =
                            ((unsigned)s << 7) | (unsigned)(d & 127);
                    }
                }
            }
        }
    }
    __syncthreads();

    // flush: 16-lane sub-group per bucket -> dense coalesced lines
    int grp = tid >> 4, lane16 = tid & 15;
    int ngrp = TPBP / 16;
    for (int b = grp; b < NB; b += ngrp) {
        int cnt = h[b];
        int sb = startb[b];
        int lim = MAXBE - sb;
        if (cnt > lim) cnt = lim;  // overflow guard (statistically unreachable)
        int gb = b * MAXBE + sb;
        int lo = lofs[b];
        for (int j = lane16; j < cnt; j += 16)
            spack[gb + j] = sorted[lo + j];
    }
}

// ---- elementwise: wx = rsqrt(deg+1) * x ----
__global__ __launch_bounds__(256) void k_wx(const float* __restrict__ x,
                                            const int* __restrict__ degn,
                                            float* __restrict__ wx, int N) {
    int i = blockIdx.x * 256 + threadIdx.x;
    if (i < N) {
        float dv = rsqrtf((float)(degn[i] + 1));
        float4 xs = reinterpret_cast<const float4*>(x)[i];
        reinterpret_cast<float4*>(wx)[i] =
            make_float4(dv * xs.x, dv * xs.y, dv * xs.z, dv * xs.w);
    }
}

// ---- fused node-sort + layer 1: spack -> LDS csr -> gather + MLP -> wt; csr/offn out ----
__global__ __launch_bounds__(TPB, 4) void k_l1f(const unsigned int* __restrict__ spack,
                                                const int* __restrict__ cursor,
                                                const float* __restrict__ wx,
                                                const float* __restrict__ W1,
                                                const float* __restrict__ b1,
                                                const float* __restrict__ W2,
                                                float* __restrict__ wt,
                                                int* __restrict__ offn,
                                                int* __restrict__ csr, int N) {
    __shared__ int lcsr[MAXBE];  // 36 KB, xor-swizzled
    __shared__ int c[NPB];
    __shared__ int excl[NPB];    // inclusive scan of c
    __shared__ float sW1[64], sb1[16], sW2[32];
    int tid = threadIdx.x;
    int b = blockIdx.x;
    if (tid < NPB) c[tid] = 0;
    if (tid < 64) sW1[tid] = W1[tid];
    else if (tid < 80) sb1[tid - 64] = b1[tid - 64];
    else if (tid < 112) sW2[tid - 80] = W2[tid - 80];
    __syncthreads();
    int beg = b * MAXBE;
    int cnt = cursor[b];
    if (cnt > MAXBE) cnt = MAXBE;

    // pass 1: read spack once; edge word + rank kept in registers
    unsigned ur[EPT];
    unsigned short rr[EPT];
#pragma unroll
    for (int k = 0; k < EPT; ++k) {
        int j = k * TPB + tid;
        if (j < cnt) {
            unsigned u = spack[beg + j];
            ur[k] = u;
            rr[k] = (unsigned short)atomicAdd(&c[u & 127], 1);
        }
    }
    __syncthreads();
    // inclusive scan c -> excl
    if (tid < NPB) excl[tid] = c[tid];
    __syncthreads();
    for (int off = 1; off < NPB; off <<= 1) {
        int add = (tid < NPB && tid >= off) ? excl[tid - off] : 0;
        __syncthreads();
        if (tid < NPB) excl[tid] += add;
        __syncthreads();
    }
    // scatter src ids into LDS csr (swizzled)
#pragma unroll
    for (int k = 0; k < EPT; ++k) {
        int j = k * TPB + tid;
        if (j < cnt) {
            unsigned u = ur[k];
            int loc = u & 127;
            int pos = (excl[loc] - c[loc]) + (int)rr[k];
            lcsr[sw(pos)] = (int)(u >> 7);
        }
    }
    if (tid < NPB) {
        int i = b * NPB + tid;
        if (i < N) offn[i] = beg + excl[tid] - c[tid];
    }
    __syncthreads();
    // coalesced csr writeback for k_l2 (stores fire-and-forget)
    for (int j = tid; j < cnt; j += TPB)
        csr[beg + j] = lcsr[sw(j)];

    // gather + MLP: 4 lanes per node, register accumulation
    int i = b * NPB + (tid >> 2);
    int sub = tid & 3;
    const float4* wxv = reinterpret_cast<const float4*>(wx);
    float a0 = 0.f, a1 = 0.f, a2 = 0.f, a3 = 0.f;
    int dg = 0, lo = 0;
    if (i < N) {
        dg = c[tid >> 2];
        lo = excl[tid >> 2] - dg;
        for (int k = sub; k < dg; k += 4) {
            int s = lcsr[sw(lo + k)];
            float4 v = wxv[s];
            a0 += v.x; a1 += v.y; a2 += v.z; a3 += v.w;
        }
    }
#pragma unroll
    for (int d = 1; d < 4; d <<= 1) {
        a0 += __shfl_xor(a0, d);
        a1 += __shfl_xor(a1, d);
        a2 += __shfl_xor(a2, d);
        a3 += __shfl_xor(a3, d);
    }
    if (sub == 0 && i < N) {
        float dv = rsqrtf((float)(dg + 1));
        float4 w4 = wxv[i];
        a0 = dv * (a0 + w4.x);
        a1 = dv * (a1 + w4.y);
        a2 = dv * (a2 + w4.z);
        a3 = dv * (a3 + w4.w);
        float t0 = 0.f, t1 = 0.f;
#pragma unroll
        for (int k = 0; k < 16; ++k) {
            float h = fmaf(a0, sW1[k],
                      fmaf(a1, sW1[16 + k],
                      fmaf(a2, sW1[32 + k],
                      fmaf(a3, sW1[48 + k], sb1[k]))));
            h = fmaxf(h, 0.f);
            t0 = fmaf(h, sW2[2 * k + 0], t0);
            t1 = fmaf(h, sW2[2 * k + 1], t1);
        }
        reinterpret_cast<float2*>(wt)[i] = make_float2(dv * t0, dv * t1);
    }
}

// ---- block-per-bucket, 4 lanes per node: LDS-staged csr gather wt -> out ----
__global__ __launch_bounds__(TPB, 4) void k_l2(const int* __restrict__ csr,
                                               const int* __restrict__ cursor,
                                               const int* __restrict__ offn,
                                               const int* __restrict__ degn,
                                               const float* __restrict__ wt,
                                               const float* __restrict__ b2,
                                               float* __restrict__ out, int N) {
    __shared__ int lsrc[MAXBE];  // 36 KB
    int tid = threadIdx.x;
    int b = blockIdx.x;
    int beg = b * MAXBE;
    int cnt = cursor[b];
    if (cnt > MAXBE) cnt = MAXBE;
    int n4 = (cnt + 3) >> 2;
    const int4* cv = reinterpret_cast<const int4*>(csr + beg);
    for (int j = tid; j < n4; j += TPB)
        reinterpret_cast<int4*>(lsrc)[sw4(j)] = cv[j];
    __syncthreads();
    int i = b * NPB + (tid >> 2);
    int sub = tid & 3;
    const float2* wtv = reinterpret_cast<const float2*>(wt);
    float s0 = 0.f, s1 = 0.f;
    int dg = 0, lo = 0;
    if (i < N) {
        dg = degn[i];
        lo = offn[i] - beg;
        for (int k = sub; k < dg; k += 4) {
            int s = lsrc[sw(lo + k)];
            float2 v = wtv[s];
            s0 += v.x; s1 += v.y;
        }
    }
#pragma unroll
    for (int d = 1; d < 4; d <<= 1) {
        s0 += __shfl_xor(s0, d);
        s1 += __shfl_xor(s1, d);
    }
    if (sub == 0 && i < N) {
        float dv = rsqrtf((float)(dg + 1));
        float2 w = wtv[i];
        out[2 * i + 0] = dv * (s0 + w.x) + b2[0];
        out[2 * i + 1] = dv * (s1 + w.y) + b2[1];
    }
}

extern "C" void kernel_launch(void* const* d_in, const int* in_sizes, int n_in,
                              void* d_out, int out_size, void* d_ws, size_t ws_size,
                              hipStream_t stream) {
    const float* x  = (const float*)d_in[0];
    const int*   ei = (const int*)d_in[1];
    const float* W1 = (const float*)d_in[2];
    const float* b1 = (const float*)d_in[3];
    const float* W2 = (const float*)d_in[4];
    const float* b2 = (const float*)d_in[5];
    float* out = (float*)d_out;

    const int N = in_sizes[0] / 4;
    const int E = in_sizes[1] / 2;
    const int* src = ei;
    const int* dst = ei + E;

    const int NB = (N + NPB - 1) / NPB;   // 782
    const int T  = (E + TILE - 1) / TILE; // 512

    char* p = (char*)d_ws;
    auto carve = [&](size_t bytes) {
        char* r = p;
        p += (bytes + 15) & ~(size_t)15;
        return (void*)r;
    };
    int* cursor = (int*)carve((size_t)NBMAX * 4);
    unsigned int* spack = (unsigned int*)carve((size_t)NB * MAXBE * 4);  // 28.8 MB
    int*   csr  = (int*)carve((size_t)NB * MAXBE * 4);                   // 28.8 MB
    float* wx   = (float*)carve((size_t)N * 4 * 4);
    float* wt   = (float*)carve((size_t)N * 2 * 4);
    int*   offn = (int*)carve((size_t)N * 4);
    int*   degn = (int*)carve((size_t)N * 4);

    hipMemsetAsync(cursor, 0, (size_t)NBMAX * 4, stream);
    hipMemsetAsync(degn, 0, (size_t)N * 4, stream);
    k_part<<<T, TPBP, 0, stream>>>(src, dst, E, NB, cursor, spack, degn);
    k_wx<<<(N + 255) / 256, 256, 0, stream>>>(x, degn, wx, N);
    k_l1f<<<NB, TPB, 0, stream>>>(spack, cursor, wx, W1, b1, W2, wt, offn, csr, N);
    k_l2<<<NB, TPB, 0, stream>>>(csr, cursor, offn, degn, wt, b2, out, N);
}

// Round 4
// 204.225 us; speedup vs baseline: 2.1347x; 2.1347x over previous
//
#include <hip/hip_runtime.h>

// N=100000, E=6400000. Buckets of 128 nodes -> NB=782.
// TILE=12500 -> T=512 tiles exactly: 2 blocks/CU uniformly (62KB LDS), no imbalance round.
constexpr int TILE  = 12500;  // edges per tile (divisible by 4)
constexpr int TPBP  = 1024;   // threads for k_part
constexpr int TPB   = 512;    // threads for k_deg / k_l1f / k_l2
constexpr int NPB   = 128;    // nodes per bucket
constexpr int NBMAX = 1024;   // LDS sizing bound for NB
constexpr int MAXBE = 9216;   // max edges per bucket (mean 8192, +11 sigma; multiple of 32)
constexpr int EPT   = MAXBE / TPB;  // 18 edges per thread in k_l1f

__device__ __forceinline__ int sw(int j)  { return j ^ (((j >> 7) & 7) << 2); }  // word swizzle
__device__ __forceinline__ int sw4(int j) { return j ^ ((j >> 5) & 7); }         // int4 swizzle

// ---- fused hist + rank(regs) + reserve + LDS-sort + 16-lane flush ----
__global__ __launch_bounds__(TPBP, 8) void k_part(const int* __restrict__ src,
                                                  const int* __restrict__ dst,
                                                  int E, int NB,
                                                  int* __restrict__ cursor,
                                                  unsigned int* __restrict__ spack) {
    __shared__ int h[NBMAX];
    __shared__ int lofs[NBMAX];
    __shared__ int startb[NBMAX];
    __shared__ unsigned int sorted[TILE];  // 50 KB

    int tid = threadIdx.x;
    int t = blockIdx.x;
    for (int j = tid; j < NBMAX; j += TPBP) h[j] = 0;
    __syncthreads();

    const int4* dv = reinterpret_cast<const int4*>(dst);
    const int4* sv = reinterpret_cast<const int4*>(src);
    int ebeg = t * TILE;
    int base4 = ebeg >> 2;
    int eend = ebeg + TILE; if (eend > E) eend = E;
    int n4t = (eend - ebeg + 3) >> 2;  // int4 slots in this tile (3125 for full tile)

    unsigned short rr[16];  // per-edge rank within (tile,bucket)

    // pass A: LDS histogram; rank kept in registers; dst re-read in pass B (L2-warm)
#pragma unroll
    for (int k = 0; k < (TILE / 4 + TPBP - 1) / TPBP; ++k) {  // 4 iters
        int idx = k * TPBP + tid;
        if (idx < n4t) {
            int i4 = base4 + idx;
            int e = i4 * 4;
            if (e + 4 <= E) {
                int4 d = dv[i4];
                rr[k * 4 + 0] = (unsigned short)atomicAdd(&h[d.x >> 7], 1);
                rr[k * 4 + 1] = (unsigned short)atomicAdd(&h[d.y >> 7], 1);
                rr[k * 4 + 2] = (unsigned short)atomicAdd(&h[d.z >> 7], 1);
                rr[k * 4 + 3] = (unsigned short)atomicAdd(&h[d.w >> 7], 1);
            } else {
#pragma unroll
                for (int j = 0; j < 4; ++j) {
                    int e2 = e + j;
                    if (e2 < E)
                        rr[k * 4 + j] = (unsigned short)atomicAdd(&h[dst[e2] >> 7], 1);
                }
            }
        }
    }
    __syncthreads();

    // reserve global space per bucket
    for (int b = tid; b < NB; b += TPBP)
        startb[b] = atomicAdd(&cursor[b], h[b]);

    // tile-local exclusive scan of h -> lofs (wave 0)
    if (tid < 64) {
        int run = 0;
        for (int c = 0; c < NBMAX; c += 64) {
            int b = c + tid;
            int v = (b < NB) ? h[b] : 0;
            int inc = v;
#pragma unroll
            for (int d = 1; d < 64; d <<= 1) {
                int o = __shfl_up(inc, d);
                if (tid >= d) inc += o;
            }
            if (b < NB) lofs[b] = run + inc - v;
            run += __shfl(inc, 63);
        }
    }
    __syncthreads();

    // pass B: re-read src/dst (L2-warm), scatter packed edges into LDS-sorted tile
#pragma unroll
    for (int k = 0; k < (TILE / 4 + TPBP - 1) / TPBP; ++k) {
        int idx = k * TPBP + tid;
        if (idx < n4t) {
            int i4 = base4 + idx;
            int e = i4 * 4;
            if (e + 4 <= E) {
                int4 d = dv[i4];
                int4 s = sv[i4];
                sorted[lofs[d.x >> 7] + (int)rr[k * 4 + 0]] = ((unsigned)s.x << 7) | (unsigned)(d.x & 127);
                sorted[lofs[d.y >> 7] + (int)rr[k * 4 + 1]] = ((unsigned)s.y << 7) | (unsigned)(d.y & 127);
                sorted[lofs[d.z >> 7] + (int)rr[k * 4 + 2]] = ((unsigned)s.z << 7) | (unsigned)(d.z & 127);
                sorted[lofs[d.w >> 7] + (int)rr[k * 4 + 3]] = ((unsigned)s.w << 7) | (unsigned)(d.w & 127);
            } else {
#pragma unroll
                for (int j = 0; j < 4; ++j) {
                    int e2 = e + j;
                    if (e2 < E) {
                        int d = dst[e2];
                        int s = src[e2];
                        sorted[lofs[d >> 7] + (int)rr[k * 4 + j]] =
                            ((unsigned)s << 7) | (unsigned)(d & 127);
                    }
                }
            }
        }
    }
    __syncthreads();

    // flush: 16-lane sub-group per bucket -> dense coalesced lines
    int grp = tid >> 4, lane16 = tid & 15;
    int ngrp = TPBP / 16;
    for (int b = grp; b < NB; b += ngrp) {
        int cnt = h[b];
        int sb = startb[b];
        int lim = MAXBE - sb;
        if (cnt > lim) cnt = lim;  // overflow guard (statistically unreachable)
        int gb = b * MAXBE + sb;
        int lo = lofs[b];
        for (int j = lane16; j < cnt; j += 16)
            spack[gb + j] = sorted[lo + j];
    }
}

// ---- per-bucket degree histogram -> degn, wx = rsqrt(deg+1)*x ----
__global__ __launch_bounds__(TPB, 8) void k_deg(const unsigned int* __restrict__ spack,
                                                const int* __restrict__ cursor,
                                                const float* __restrict__ x, int N,
                                                float* __restrict__ wx,
                                                int* __restrict__ degn) {
    __shared__ int c[NPB];
    int tid = threadIdx.x;
    int b = blockIdx.x;
    if (tid < NPB) c[tid] = 0;
    __syncthreads();
    int beg = b * MAXBE;
    int cnt = cursor[b];
    if (cnt > MAXBE) cnt = MAXBE;
    int n4 = cnt >> 2;
    const int4* pv = reinterpret_cast<const int4*>(spack + beg);
    for (int j = tid; j < n4; j += TPB) {
        int4 u = pv[j];
        atomicAdd(&c[u.x & 127], 1);
        atomicAdd(&c[u.y & 127], 1);
        atomicAdd(&c[u.z & 127], 1);
        atomicAdd(&c[u.w & 127], 1);
    }
    for (int e = beg + (n4 << 2) + tid; e < beg + cnt; e += TPB)
        atomicAdd(&c[spack[e] & 127], 1);
    __syncthreads();
    if (tid < NPB) {
        int i = b * NPB + tid;
        if (i < N) {
            int dg = c[tid];
            degn[i] = dg;
            float dv = rsqrtf((float)(dg + 1));
            float4 xs = reinterpret_cast<const float4*>(x)[i];
            reinterpret_cast<float4*>(wx)[i] =
                make_float4(dv * xs.x, dv * xs.y, dv * xs.z, dv * xs.w);
        }
    }
}

// ---- fused node-sort + layer 1: spack -> LDS csr -> gather + MLP -> wt; csr/offn out ----
__global__ __launch_bounds__(TPB, 4) void k_l1f(const unsigned int* __restrict__ spack,
                                                const int* __restrict__ cursor,
                                                const float* __restrict__ wx,
                                                const float* __restrict__ W1,
                                                const float* __restrict__ b1,
                                                const float* __restrict__ W2,
                                                float* __restrict__ wt,
                                                int* __restrict__ offn,
                                                int* __restrict__ csr, int N) {
    __shared__ int lcsr[MAXBE];  // 36 KB, xor-swizzled
    __shared__ int c[NPB];
    __shared__ int excl[NPB];    // inclusive scan of c
    __shared__ float sW1[64], sb1[16], sW2[32];
    int tid = threadIdx.x;
    int b = blockIdx.x;
    if (tid < NPB) c[tid] = 0;
    if (tid < 64) sW1[tid] = W1[tid];
    else if (tid < 80) sb1[tid - 64] = b1[tid - 64];
    else if (tid < 112) sW2[tid - 80] = W2[tid - 80];
    __syncthreads();
    int beg = b * MAXBE;
    int cnt = cursor[b];
    if (cnt > MAXBE) cnt = MAXBE;

    // pass 1: read spack once; edge word + rank kept in registers
    unsigned ur[EPT];
    unsigned short rr[EPT];
#pragma unroll
    for (int k = 0; k < EPT; ++k) {
        int j = k * TPB + tid;
        if (j < cnt) {
            unsigned u = spack[beg + j];
            ur[k] = u;
            rr[k] = (unsigned short)atomicAdd(&c[u & 127], 1);
        }
    }
    __syncthreads();
    // inclusive scan c -> excl
    if (tid < NPB) excl[tid] = c[tid];
    __syncthreads();
    for (int off = 1; off < NPB; off <<= 1) {
        int add = (tid < NPB && tid >= off) ? excl[tid - off] : 0;
        __syncthreads();
        if (tid < NPB) excl[tid] += add;
        __syncthreads();
    }
    // scatter src ids into LDS csr (swizzled)
#pragma unroll
    for (int k = 0; k < EPT; ++k) {
        int j = k * TPB + tid;
        if (j < cnt) {
            unsigned u = ur[k];
            int loc = u & 127;
            int pos = (excl[loc] - c[loc]) + (int)rr[k];
            lcsr[sw(pos)] = (int)(u >> 7);
        }
    }
    if (tid < NPB) {
        int i = b * NPB + tid;
        if (i < N) offn[i] = beg + excl[tid] - c[tid];
    }
    __syncthreads();
    // coalesced csr writeback for k_l2 (stores fire-and-forget)
    for (int j = tid; j < cnt; j += TPB)
        csr[beg + j] = lcsr[sw(j)];

    // gather + MLP: 4 lanes per node, register accumulation
    int i = b * NPB + (tid >> 2);
    int sub = tid & 3;
    const float4* wxv = reinterpret_cast<const float4*>(wx);
    float a0 = 0.f, a1 = 0.f, a2 = 0.f, a3 = 0.f;
    int dg = 0, lo = 0;
    if (i < N) {
        dg = c[tid >> 2];
        lo = excl[tid >> 2] - dg;
        for (int k = sub; k < dg; k += 4) {
            int s = lcsr[sw(lo + k)];
            float4 v = wxv[s];
            a0 += v.x; a1 += v.y; a2 += v.z; a3 += v.w;
        }
    }
#pragma unroll
    for (int d = 1; d < 4; d <<= 1) {
        a0 += __shfl_xor(a0, d);
        a1 += __shfl_xor(a1, d);
        a2 += __shfl_xor(a2, d);
        a3 += __shfl_xor(a3, d);
    }
    if (sub == 0 && i < N) {
        float dv = rsqrtf((float)(dg + 1));
        float4 w4 = wxv[i];
        a0 = dv * (a0 + w4.x);
        a1 = dv * (a1 + w4.y);
        a2 = dv * (a2 + w4.z);
        a3 = dv * (a3 + w4.w);
        float t0 = 0.f, t1 = 0.f;
#pragma unroll
        for (int k = 0; k < 16; ++k) {
            float h = fmaf(a0, sW1[k],
                      fmaf(a1, sW1[16 + k],
                      fmaf(a2, sW1[32 + k],
                      fmaf(a3, sW1[48 + k], sb1[k]))));
            h = fmaxf(h, 0.f);
            t0 = fmaf(h, sW2[2 * k + 0], t0);
            t1 = fmaf(h, sW2[2 * k + 1], t1);
        }
        reinterpret_cast<float2*>(wt)[i] = make_float2(dv * t0, dv * t1);
    }
}

// ---- block-per-bucket, 4 lanes per node: LDS-staged csr gather wt -> out ----
__global__ __launch_bounds__(TPB, 4) void k_l2(const int* __restrict__ csr,
                                               const int* __restrict__ cursor,
                                               const int* __restrict__ offn,
                                               const int* __restrict__ degn,
                                               const float* __restrict__ wt,
                                               const float* __restrict__ b2,
                                               float* __restrict__ out, int N) {
    __shared__ int lsrc[MAXBE];  // 36 KB
    int tid = threadIdx.x;
    int b = blockIdx.x;
    int beg = b * MAXBE;
    int cnt = cursor[b];
    if (cnt > MAXBE) cnt = MAXBE;
    int n4 = (cnt + 3) >> 2;
    const int4* cv = reinterpret_cast<const int4*>(csr + beg);
    for (int j = tid; j < n4; j += TPB)
        reinterpret_cast<int4*>(lsrc)[sw4(j)] = cv[j];
    __syncthreads();
    int i = b * NPB + (tid >> 2);
    int sub = tid & 3;
    const float2* wtv = reinterpret_cast<const float2*>(wt);
    float s0 = 0.f, s1 = 0.f;
    int dg = 0, lo = 0;
    if (i < N) {
        dg = degn[i];
        lo = offn[i] - beg;
        for (int k = sub; k < dg; k += 4) {
            int s = lsrc[sw(lo + k)];
            float2 v = wtv[s];
            s0 += v.x; s1 += v.y;
        }
    }
#pragma unroll
    for (int d = 1; d < 4; d <<= 1) {
        s0 += __shfl_xor(s0, d);
        s1 += __shfl_xor(s1, d);
    }
    if (sub == 0 && i < N) {
        float dv = rsqrtf((float)(dg + 1));
        float2 w = wtv[i];
        out[2 * i + 0] = dv * (s0 + w.x) + b2[0];
        out[2 * i + 1] = dv * (s1 + w.y) + b2[1];
    }
}

extern "C" void kernel_launch(void* const* d_in, const int* in_sizes, int n_in,
                              void* d_out, int out_size, void* d_ws, size_t ws_size,
                              hipStream_t stream) {
    const float* x  = (const float*)d_in[0];
    const int*   ei = (const int*)d_in[1];
    const float* W1 = (const float*)d_in[2];
    const float* b1 = (const float*)d_in[3];
    const float* W2 = (const float*)d_in[4];
    const float* b2 = (const float*)d_in[5];
    float* out = (float*)d_out;

    const int N = in_sizes[0] / 4;
    const int E = in_sizes[1] / 2;
    const int* src = ei;
    const int* dst = ei + E;

    const int NB = (N + NPB - 1) / NPB;   // 782
    const int T  = (E + TILE - 1) / TILE; // 512

    char* p = (char*)d_ws;
    auto carve = [&](size_t bytes) {
        char* r = p;
        p += (bytes + 15) & ~(size_t)15;
        return (void*)r;
    };
    int* cursor = (int*)carve((size_t)NBMAX * 4);
    unsigned int* spack = (unsigned int*)carve((size_t)NB * MAXBE * 4);  // 28.8 MB
    int*   csr  = (int*)carve((size_t)NB * MAXBE * 4);                   // 28.8 MB
    float* wx   = (float*)carve((size_t)N * 4 * 4);
    float* wt   = (float*)carve((size_t)N * 2 * 4);
    int*   offn = (int*)carve((size_t)N * 4);
    int*   degn = (int*)carve((size_t)N * 4);

    hipMemsetAsync(cursor, 0, (size_t)NBMAX * 4, stream);
    k_part<<<T, TPBP, 0, stream>>>(src, dst, E, NB, cursor, spack);
    k_deg<<<NB, TPB, 0, stream>>>(spack, cursor, x, N, wx, degn);
    k_l1f<<<NB, TPB, 0, stream>>>(spack, cursor, wx, W1, b1, W2, wt, offn, csr, N);
    k_l2<<<NB, TPB, 0, stream>>>(csr, cursor, offn, degn, wt, b2, out, N);
}